// Round 1
// baseline (114.623 us; speedup 1.0000x reference)
//
#include <hip/hip_runtime.h>

// PatchManifoldLossPre: resize (8,19,512,512) -> (8,19,48,48) with jax.image.resize
// bilinear (antialias=True, triangle kernel, half-pixel centers), split into 4x4
// patches of 12x12, P[16, 21888], value = mean(weights * pairwise-MSD(P)) .
// pairwise-MSD via Gram: map[a,b] = (G[aa]+G[bb]-2G[ab])/N.

#define HIN 512
#define WIN 512
#define HOUT 48
#define WOUT 48
#define NTAP 22
#define NBC 152          // 8*19
#define GROUP 12         // output rows per resize block
#define NGROUPS 4
#define MAXROWS 140      // max input-row span per group (measured: 139)
#define CHUNK 8
#define KS (512.0 / 48.0)

// Triangle-kernel resize weights matching jax.image.resize(method="bilinear",
// antialias=True): sample s=(i+0.5)*KS-0.5, kernel_scale=KS, normalize over
// valid taps. Window of NTAP taps clamped into [lo, hi) so inner loops need
// no bounds checks; taps dropped/added by the clamp all have zero weight.
__device__ __forceinline__ void compute_weights(int i, int lo, int hi,
                                                int* start_out, float* w_out,
                                                int wstride) {
  double s = (i + 0.5) * KS - 0.5;
  int st = (int)ceil(s - KS);
  int stc = st;
  if (stc < lo) stc = lo;
  if (stc > hi - NTAP) stc = hi - NTAP;
  double wr[NTAP];
  double sum = 0.0;
#pragma unroll
  for (int k = 0; k < NTAP; ++k) {
    int j = stc + k;
    double d = fabs(s - (double)j) * (1.0 / KS);
    double w = 1.0 - d;
    if (w < 0.0) w = 0.0;
    if (j < 0 || j >= HIN) w = 0.0;  // global validity (normalization excludes OOB)
    wr[k] = w;
    sum += w;
  }
  double inv = 1.0 / sum;
#pragma unroll
  for (int k = 0; k < NTAP; ++k) w_out[k * wstride] = (float)(wr[k] * inv);
  *start_out = stc;
}

// One block per (bc, group-of-12-output-rows). Stages input rows in LDS,
// horizontal 22-tap pass -> tmp, vertical 22-tap pass -> smallimg (d_ws).
__global__ __launch_bounds__(256, 3) void k_resize(const float* __restrict__ pred,
                                                   float* __restrict__ smallimg) {
  __shared__ float tmp[MAXROWS][WOUT];     // 26880 B
  __shared__ float rowbuf[CHUNK][WIN];     // 16384 B
  __shared__ float hw[NTAP][WOUT];         // 4224 B (transposed: conflict-free reads)
  __shared__ float vw[NTAP][GROUP];        // 1056 B
  __shared__ int hstart[WOUT];
  __shared__ int vstart[GROUP];            // tmp-relative clamped start
  __shared__ int sbounds[2];

  const int tid = threadIdx.x;
  const int bc = blockIdx.x >> 2;
  const int grp = blockIdx.x & 3;
  const int oy0 = grp * GROUP;

  if (tid == 0) {
    double s0 = (oy0 + 0.5) * KS - 0.5;
    int plo = (int)ceil(s0 - KS);
    if (plo < 0) plo = 0;
    double s1 = (oy0 + GROUP - 0.5) * KS - 0.5;
    int phi = (int)ceil(s1 - KS) + NTAP;
    if (phi > HIN) phi = HIN;
    sbounds[0] = plo;
    sbounds[1] = phi;
  }
  if (tid < WOUT) {
    compute_weights(tid, 0, WIN, &hstart[tid], &hw[0][tid], WOUT);
  }
  __syncthreads();  // publish plo/phi (needed for vertical clamp range) + hw/hstart
  const int plo = sbounds[0];
  const int phi = sbounds[1];
  if (tid >= 64 && tid < 64 + GROUP) {
    const int r = tid - 64;
    int vs;
    compute_weights(oy0 + r, plo, phi, &vs, &vw[0][r], GROUP);
    vstart[r] = vs - plo;
  }

  const float* img = pred + (size_t)bc * (HIN * WIN);
  for (int base = plo; base < phi; base += CHUNK) {
    const int rows = min(CHUNK, phi - base);
    __syncthreads();  // rowbuf free to overwrite (first iter: also fences vw/vstart)
    for (int idx = tid; idx < rows * (WIN / 4); idx += 256) {
      const int r = idx >> 7;          // WIN/4 == 128
      const int q = (idx & 127) << 2;
      *reinterpret_cast<float4*>(&rowbuf[r][q]) =
          *reinterpret_cast<const float4*>(img + (size_t)(base + r) * WIN + q);
    }
    __syncthreads();
    for (int idx = tid; idx < rows * WOUT; idx += 256) {
      const int r = idx / WOUT;
      const int j = idx - r * WOUT;
      const int st = hstart[j];
      float acc = 0.f;
#pragma unroll
      for (int k = 0; k < NTAP; ++k) acc += hw[k][j] * rowbuf[r][st + k];
      tmp[base - plo + r][j] = acc;
    }
  }
  __syncthreads();

  for (int idx = tid; idx < GROUP * WOUT; idx += 256) {
    const int r = idx / WOUT;
    const int ox = idx - r * WOUT;
    const int vs = vstart[r];
    float acc = 0.f;
#pragma unroll
    for (int k = 0; k < NTAP; ++k) acc += vw[k][r] * tmp[vs + k][ox];
    smallimg[(size_t)bc * (HOUT * WOUT) + (oy0 + r) * WOUT + ox] = acc;
  }
}

// One block per (b,c): stage 48x48 image in LDS, each thread owns pair
// (a,b)=(tid>>4,tid&15), accumulates sum over 12x12 positions of v_a*v_b.
__global__ __launch_bounds__(256) void k_gram(const float* __restrict__ smallimg,
                                              float* __restrict__ G) {
  __shared__ float img[HOUT * WOUT];
  const int tid = threadIdx.x;
  const float* src = smallimg + (size_t)blockIdx.x * (HOUT * WOUT);
  for (int idx = tid; idx < (HOUT * WOUT) / 4; idx += 256) {
    *reinterpret_cast<float4*>(&img[idx * 4]) =
        *reinterpret_cast<const float4*>(src + idx * 4);
  }
  __syncthreads();
  const int a = tid >> 4;
  const int b = tid & 15;
  const float* pa = &img[((a >> 2) * GROUP) * WOUT + (a & 3) * GROUP];
  const float* pb = &img[((b >> 2) * GROUP) * WOUT + (b & 3) * GROUP];
  float acc = 0.f;
  for (int y = 0; y < GROUP; ++y) {
#pragma unroll
    for (int x = 0; x < GROUP; ++x) {
      acc += pa[y * WOUT + x] * pb[y * WOUT + x];
    }
  }
  atomicAdd(&G[tid], acc);
}

// value = sum_{a,b} w[a,b]*(G[aa]+G[bb]-2G[ab]) / (256*N),  N = 152*144
__global__ __launch_bounds__(256) void k_final(const float* __restrict__ G,
                                               const float* __restrict__ wts,
                                               float* __restrict__ out) {
  __shared__ float partial[4];
  const int tid = threadIdx.x;
  const int a = tid >> 4;
  const int b = tid & 15;
  float v = wts[tid] * (G[a * 17] + G[b * 17] - 2.0f * G[tid]);
#pragma unroll
  for (int off = 32; off > 0; off >>= 1) v += __shfl_down(v, off, 64);
  if ((tid & 63) == 0) partial[tid >> 6] = v;
  __syncthreads();
  if (tid == 0) {
    out[0] = (partial[0] + partial[1] + partial[2] + partial[3]) *
             (float)(1.0 / (256.0 * 21888.0));
  }
}

extern "C" void kernel_launch(void* const* d_in, const int* in_sizes, int n_in,
                              void* d_out, int out_size, void* d_ws, size_t ws_size,
                              hipStream_t stream) {
  const float* pred = (const float*)d_in[0];
  const float* wts = (const float*)d_in[1];
  float* out = (float*)d_out;
  float* G = (float*)d_ws;                              // 256 floats
  float* smallimg = (float*)((char*)d_ws + 1024);       // 152*48*48 floats = 1.4 MB

  hipMemsetAsync(G, 0, 256 * sizeof(float), stream);
  hipLaunchKernelGGL(k_resize, dim3(NBC * NGROUPS), dim3(256), 0, stream, pred, smallimg);
  hipLaunchKernelGGL(k_gram, dim3(NBC), dim3(256), 0, stream, smallimg, G);
  hipLaunchKernelGGL(k_final, dim3(1), dim3(256), 0, stream, G, wts, out);
}

// Round 2
// 52.555 us; speedup vs baseline: 2.1810x; 2.1810x over previous
//
#include <hip/hip_runtime.h>

// PatchManifoldLossPre: resize (8,19,512,512) -> (8,19,48,48) with jax.image.resize
// bilinear (antialias=True, triangle kernel, half-pixel centers), split into 4x4
// patches of 12x12, P[16, 21888], value = mean(weights * pairwise-MSD(P)).
// pairwise-MSD via Gram: map[a,b] = (G[aa]+G[bb]-2G[ab])/N.
//
// Round-2 structure: vertical-first resize (coalesced global float4 reads, no LDS,
// no barriers), then horizontal gather from a swizzled LDS tile (c -> c + 4*(c>>5),
// row stride 580) which keeps ds_read bank conflicts at ~2-way (free) instead of
// the 16-way conflict of the round-1 row-major layout (st(j+3)=st(j)+32).

#define HIN 512
#define WOUT 48
#define NTAP 22
#define NBC 152          // 8*19
#define GRP 6            // output rows per resize block
#define NGRP 8
#define TSTRIDE 580      // padded LDS row stride in floats (512 + 4*16 + 4)
#define GROUP 12         // patch size
#define KS (512.0 / 48.0)

// Triangle-kernel resize weights matching jax.image.resize(method="bilinear",
// antialias=True): sample s=(i+0.5)*KS-0.5, kernel scale KS, normalize over valid
// taps. Window clamped into [0, HIN-NTAP]; clamped-in taps all have zero weight.
__device__ __forceinline__ int compute_weights(int i, float* w) {
  double s = (i + 0.5) * KS - 0.5;
  int stc = (int)ceil(s - KS);
  if (stc < 0) stc = 0;
  if (stc > HIN - NTAP) stc = HIN - NTAP;
  double wr[NTAP];
  double sum = 0.0;
#pragma unroll
  for (int k = 0; k < NTAP; ++k) {
    int j = stc + k;
    double d = fabs(s - (double)j) * (1.0 / KS);
    double wv = 1.0 - d;
    if (wv < 0.0) wv = 0.0;
    if (j >= HIN) wv = 0.0;  // j<0 impossible after clamp
    wr[k] = wv;
    sum += wv;
  }
  double inv = 1.0 / sum;
#pragma unroll
  for (int k = 0; k < NTAP; ++k) w[k] = (float)(wr[k] * inv);
  return stc;
}

__global__ __launch_bounds__(256, 4) void k_resize(const float* __restrict__ pred,
                                                   float* __restrict__ smallimg) {
  __shared__ float tile[GRP * TSTRIDE];  // 13920 B, swizzled rows
  __shared__ float hw[NTAP][WOUT];       // 4224 B (lanes j consecutive: conflict-free)
  __shared__ float vw[GRP][NTAP];        // 528 B (wave-uniform reads: broadcast)
  __shared__ int hst[WOUT];
  __shared__ int vst[GRP];

  const int t = threadIdx.x;
  const int bc = blockIdx.x >> 3;
  const int oy0 = (blockIdx.x & 7) * GRP;

  {
    float wreg[NTAP];
    if (t < WOUT) {
      hst[t] = compute_weights(t, wreg);
#pragma unroll
      for (int k = 0; k < NTAP; ++k) hw[k][t] = wreg[k];
    } else if (t < WOUT + GRP) {
      const int r = t - WOUT;
      vst[r] = compute_weights(oy0 + r, wreg);
#pragma unroll
      for (int k = 0; k < NTAP; ++k) vw[r][k] = wreg[k];
    }
  }
  __syncthreads();

  // Vertical pass: each thread owns one float4 column slice for 3 output rows.
  // Global reads are 1KB-contiguous per wave; adjacent oy windows overlap ~11 of
  // 22 rows -> L1 reuse. Results go to the swizzled LDS tile.
  const float* img = pred + (size_t)bc * (HIN * HIN);
  const int slot = t >> 7;        // 0..1
  const int x = (t & 127) << 2;   // 0..508
  const int xph = x + ((x >> 5) << 2);
#pragma unroll
  for (int i = 0; i < 3; ++i) {
    const int r = slot * 3 + i;
    const int base = vst[r];
    float4 a = make_float4(0.f, 0.f, 0.f, 0.f);
#pragma unroll
    for (int k = 0; k < NTAP; ++k) {
      const float4 v =
          *reinterpret_cast<const float4*>(img + (size_t)(base + k) * HIN + x);
      const float wk = vw[r][k];
      a.x = fmaf(wk, v.x, a.x);
      a.y = fmaf(wk, v.y, a.y);
      a.z = fmaf(wk, v.z, a.z);
      a.w = fmaf(wk, v.w, a.w);
    }
    *reinterpret_cast<float4*>(&tile[r * TSTRIDE + xph]) = a;
  }
  __syncthreads();

  // Horizontal gather from swizzled tile -> smallimg (coalesced stores).
  for (int it = 0; it < 2; ++it) {
    const int item = it * 256 + t;
    if (item >= GRP * WOUT) break;
    const int r = item / WOUT;
    const int j = item - r * WOUT;
    const int stc = hst[j];
    const int rb = r * TSTRIDE;
    float acc = 0.f;
#pragma unroll
    for (int k = 0; k < NTAP; ++k) {
      const int cc = stc + k;
      acc = fmaf(hw[k][j], tile[rb + cc + ((cc >> 5) << 2)], acc);
    }
    smallimg[(size_t)bc * (WOUT * WOUT) + (oy0 + r) * WOUT + j] = acc;
  }
}

// One block per (b,c): stage 48x48 image in LDS, each thread owns pair
// (a,b)=(tid>>4,tid&15), accumulates sum over 12x12 positions of v_a*v_b.
__global__ __launch_bounds__(256) void k_gram(const float* __restrict__ smallimg,
                                              float* __restrict__ G) {
  __shared__ float img[WOUT * WOUT];
  const int tid = threadIdx.x;
  const float* src = smallimg + (size_t)blockIdx.x * (WOUT * WOUT);
  for (int idx = tid; idx < (WOUT * WOUT) / 4; idx += 256) {
    *reinterpret_cast<float4*>(&img[idx * 4]) =
        *reinterpret_cast<const float4*>(src + idx * 4);
  }
  __syncthreads();
  const int a = tid >> 4;
  const int b = tid & 15;
  const float* pa = &img[((a >> 2) * GROUP) * WOUT + (a & 3) * GROUP];
  const float* pb = &img[((b >> 2) * GROUP) * WOUT + (b & 3) * GROUP];
  float acc = 0.f;
  for (int y = 0; y < GROUP; ++y) {
#pragma unroll
    for (int x = 0; x < GROUP; ++x) {
      acc += pa[y * WOUT + x] * pb[y * WOUT + x];
    }
  }
  atomicAdd(&G[tid], acc);
}

// value = sum_{a,b} w[a,b]*(G[aa]+G[bb]-2G[ab]) / (256*N),  N = 152*144
__global__ __launch_bounds__(256) void k_final(const float* __restrict__ G,
                                               const float* __restrict__ wts,
                                               float* __restrict__ out) {
  __shared__ float partial[4];
  const int tid = threadIdx.x;
  const int a = tid >> 4;
  const int b = tid & 15;
  float v = wts[tid] * (G[a * 17] + G[b * 17] - 2.0f * G[tid]);
#pragma unroll
  for (int off = 32; off > 0; off >>= 1) v += __shfl_down(v, off, 64);
  if ((tid & 63) == 0) partial[tid >> 6] = v;
  __syncthreads();
  if (tid == 0) {
    out[0] = (partial[0] + partial[1] + partial[2] + partial[3]) *
             (float)(1.0 / (256.0 * 21888.0));
  }
}

extern "C" void kernel_launch(void* const* d_in, const int* in_sizes, int n_in,
                              void* d_out, int out_size, void* d_ws, size_t ws_size,
                              hipStream_t stream) {
  const float* pred = (const float*)d_in[0];
  const float* wts = (const float*)d_in[1];
  float* out = (float*)d_out;
  float* G = (float*)d_ws;                         // 256 floats
  float* smallimg = (float*)((char*)d_ws + 1024);  // 152*48*48 floats

  hipMemsetAsync(G, 0, 256 * sizeof(float), stream);
  hipLaunchKernelGGL(k_resize, dim3(NBC * NGRP), dim3(256), 0, stream, pred, smallimg);
  hipLaunchKernelGGL(k_gram, dim3(NBC), dim3(256), 0, stream, smallimg, G);
  hipLaunchKernelGGL(k_final, dim3(1), dim3(256), 0, stream, G, wts, out);
}